// Round 12
// baseline (17.424 us; speedup 1.0000x reference)
//
#include <hip/hip_runtime.h>

// TransformerBlockQuantum: B=32, S=4096, E=8, F=512, fp32 in/out.
// Full-MFMA, F-SPLIT kernel. 512 threads (8 waves), 128 tokens/block,
// grid 1024 (4 blocks/CU launched, 2 co-resident -> staging overlaps compute).
// Wave w serves token group g = w&3 (32 tokens); fhalf = w>>2 picks FFN
// chunk range [8*fhalf, 8*fhalf+8). Lanes l / l+32 serve token (l&31);
// hi = l>>5 picks the e-half / K-half. Wave pair (g, fhalf=0/1) merges
// FFN partials via LDS red[] + 1 barrier (b1-via-K-slots is per-chunk
// self-contained, so the F-split is exact).
//
//  attn:  D1 = Win·x^T (+theta via K-slots 8/9 vs const 1.0)  [1 mfma]
//         q = cos(D1 regs0-3);  D2 = Wout·q + C(=x residual)  [1 mfma]
//  LN1:   half-split: lane reduces its native 4 elems, cross-half via
//         2x shfl_xor partial sums; E[x^2]-m^2 variance.
//  qf:    4 cos/lane * cth table -> 2 packed words -> 2 shfl -> B-frag.
//  FFN/chunk c:  mid = wab·qf (b1 via K8/9)  [1 mfma, 1 ds];
//         relu = fmaxf + cvt_pk (v_pk_max_i16 = round-8 bug, banned;
//         global-wab-via-prep-kernel = round-10 bug, banned);
//         dual accumulators accA/accB; 8 chunks per wave (F-split).
//  merge: fhalf=1 writes acc partial (f32x4/lane) to red; barrier;
//         fhalf=0 adds it, then +b2, half-split LN2, coalesced f32x4 store.

typedef __attribute__((ext_vector_type(8)))  short short8;
typedef __attribute__((ext_vector_type(4)))  float f32x4;
typedef __attribute__((ext_vector_type(16))) float f32x16;
typedef __attribute__((ext_vector_type(4)))  int   int4v;

constexpr int E   = 8;
constexpr int F   = 512;
constexpr int TPB = 128;            // tokens per block

static __device__ __forceinline__ int cvt_pk_bf16(float lo, float hi) {
    int r;
    asm("v_cvt_pk_bf16_f32 %0, %1, %2" : "=v"(r) : "v"(lo), "v"(hi));
    return r;
}

// pack {bf16_hi(v), bf16(v - hi)} into one word (K-slot pair vs 1.0,1.0)
static __device__ __forceinline__ int hilo_bf16(float v) {
    unsigned u = __builtin_bit_cast(unsigned, v);
    float fh = __builtin_bit_cast(float, u & 0xFFFF0000u);
    return cvt_pk_bf16(fh, v - fh);
}

__global__ __launch_bounds__(512, 4) void qtb_kernel(
    const float* __restrict__ x,
    const float* __restrict__ Win,
    const float* __restrict__ th_attn,
    const float* __restrict__ Wout,
    const float* __restrict__ th_ffn,
    const float* __restrict__ W1,
    const float* __restrict__ b1,
    const float* __restrict__ W2,
    const float* __restrict__ b2,
    const float* __restrict__ g1, const float* __restrict__ bb1,
    const float* __restrict__ g2, const float* __restrict__ bb2,
    float* __restrict__ out, int ntok)
{
    __shared__ short8 wab[1024];    // [c][0-31: W1 row 32c+r | 32-63: b1 rec]
    __shared__ short8 w2p[512];     // [c][m][hi][e8] K-permuted W2 recs
    __shared__ short8 attnA[64];    // Win rows / theta recs
    __shared__ short8 woutp[64];    // Wout K-permuted recs
    __shared__ __align__(16) float cth_lds[8];   // cos(th_ffn)
    __shared__ f32x4 red[4][64];    // FFN partials from fhalf=1 waves (4 KB)

    const int tid  = threadIdx.x;
    const int lane = tid & 63;
    const int wv   = tid >> 6;        // 0..7
    const int g    = wv & 3;          // token group
    const int fh2  = wv >> 2;         // F-half: 0 -> chunks 0-7, 1 -> 8-15
    const int t32  = lane & 31;
    const int hi   = lane >> 5;
    const int e8   = t32 & 7;

    // ---------------- stage weights (each of 512 threads: 1 of each) ------
    {
        // W1 row `tid` -> wab[64*(tid>>5) + (tid&31)]
        const f32x4* w1v = reinterpret_cast<const f32x4*>(W1 + tid * 8);
        f32x4 a = w1v[0], b = w1v[1];
        int4v rw1 = { cvt_pk_bf16(a[0], a[1]), cvt_pk_bf16(a[2], a[3]),
                      cvt_pk_bf16(b[0], b[1]), cvt_pk_bf16(b[2], b[3]) };
        wab[((tid >> 5) << 6) + (tid & 31)] = __builtin_bit_cast(short8, rw1);
        // b1 row `tid` -> wab[.. + 32 + ..]  (hi/lo split, K-slots 8/9)
        int4v rb1 = { hilo_bf16(b1[tid]), 0, 0, 0 };
        wab[((tid >> 5) << 6) + 32 + (tid & 31)] = __builtin_bit_cast(short8, rb1);
        // W2 K-permuted rec `tid`
        const int se = tid & 7, sh = (tid >> 3) & 1, sm = (tid >> 4) & 1, sc = tid >> 5;
        const int f0 = sc * 32 + sm * 16 + sh * 4;
        const float* wp = W2 + se * F + f0;
        f32x4 p = *reinterpret_cast<const f32x4*>(wp);
        f32x4 q = *reinterpret_cast<const f32x4*>(wp + 8);
        int4v rw2 = { cvt_pk_bf16(p[0], p[1]), cvt_pk_bf16(p[2], p[3]),
                      cvt_pk_bf16(q[0], q[1]), cvt_pk_bf16(q[2], q[3]) };
        w2p[tid] = __builtin_bit_cast(short8, rw2);

        if (tid < 8) cth_lds[tid] = __cosf(th_ffn[tid]);

        if (tid < 64) {           // attnA: lanes 0-31 Win rows, 32-63 theta recs
            const int tt = tid & 31;
            int4v ra = { 0, 0, 0, 0 };
            if (tt < 8) {
                if (tid < 32) {
                    const f32x4* wiv = reinterpret_cast<const f32x4*>(Win + tt * 8);
                    f32x4 wa = wiv[0], wb = wiv[1];
                    ra = int4v{ cvt_pk_bf16(wa[0], wa[1]), cvt_pk_bf16(wa[2], wa[3]),
                                cvt_pk_bf16(wb[0], wb[1]), cvt_pk_bf16(wb[2], wb[3]) };
                } else {
                    ra = int4v{ hilo_bf16(th_attn[tt]), 0, 0, 0 };
                }
            }
            attnA[tid] = __builtin_bit_cast(short8, ra);
        } else if (tid < 128) {   // woutp: rec (t32, hh) = {Wout[t32][4hh..+3]}
            const int l = tid - 64, tt = l & 31, hh = l >> 5;
            int4v ro = { 0, 0, 0, 0 };
            if (tt < 8) {
                const float* wo = Wout + tt * 8 + hh * 4;
                ro.x = cvt_pk_bf16(wo[0], wo[1]);
                ro.y = cvt_pk_bf16(wo[2], wo[3]);
            }
            woutp[l] = __builtin_bit_cast(short8, ro);
        }
    }
    __syncthreads();

    // ---------------- per-wave front (both F-halves duplicate attn) -------
    const int T = blockIdx.x * TPB + g * 32 + t32;
    const bool valid = (T < ntok);
    const int ONE2 = 0x3F803F80;            // two bf16 1.0
    const f32x16 z16 = {};

    f32x4 x0 = {0.f,0.f,0.f,0.f}, x1 = {0.f,0.f,0.f,0.f};
    if (valid) {
        const f32x4* xv = reinterpret_cast<const f32x4*>(x + (size_t)T * E);
        x0 = xv[0]; x1 = xv[1];
    }

    // ---- attention GEMM1: D1 = Win·x^T + theta ----
    int4v bx = hi ? int4v{ ONE2, 0, 0, 0 }
                  : int4v{ cvt_pk_bf16(x0[0], x0[1]), cvt_pk_bf16(x0[2], x0[3]),
                           cvt_pk_bf16(x1[0], x1[1]), cvt_pk_bf16(x1[2], x1[3]) };
    short8 aA = attnA[lane];
    f32x16 d1 = __builtin_amdgcn_mfma_f32_32x32x16_bf16(
        aA, __builtin_bit_cast(short8, bx), z16, 0, 0, 0);

    float qv0 = __cosf(d1[0]), qv1 = __cosf(d1[1]);
    float qv2 = __cosf(d1[2]), qv3 = __cosf(d1[3]);

    // ---- attention GEMM2: D2 = Wout·q + x (residual via C) ----
    int q01 = cvt_pk_bf16(qv0, qv1), q23 = cvt_pk_bf16(qv2, qv3);
    int4v bq2 = { q01, q23, q01, q23 };
    short8 aO = woutp[lane];
    f32x16 c2 = z16;
    c2[0] = hi ? x1[0] : x0[0];
    c2[1] = hi ? x1[1] : x0[1];
    c2[2] = hi ? x1[2] : x0[2];
    c2[3] = hi ? x1[3] : x0[3];
    f32x16 d2 = __builtin_amdgcn_mfma_f32_32x32x16_bf16(
        aO, __builtin_bit_cast(short8, bq2), c2, 0, 0, 0);

    // ---- half-split LN1 ----
    float s0 = d2[0], s1 = d2[1], s2 = d2[2], s3 = d2[3];
    float ps = s0 + s1 + s2 + s3;
    float pq = s0*s0 + s1*s1 + s2*s2 + s3*s3;
    float mn = (ps + __shfl_xor(ps, 32)) * 0.125f;
    float vr = (pq + __shfl_xor(pq, 32)) * 0.125f - mn * mn;
    float rs = rsqrtf(vr + 1e-5f);
    float hn[4];
    hn[0] = (s0 - mn) * rs * g1[4 * hi + 0] + bb1[4 * hi + 0];
    hn[1] = (s1 - mn) * rs * g1[4 * hi + 1] + bb1[4 * hi + 1];
    hn[2] = (s2 - mn) * rs * g1[4 * hi + 2] + bb1[4 * hi + 2];
    hn[3] = (s3 - mn) * rs * g1[4 * hi + 3] + bb1[4 * hi + 3];

    // ---- qf + B-frag via 2 shfl ----
    f32x4 cthv = *reinterpret_cast<const f32x4*>(&cth_lds[hi * 4]);
    float qf0 = __cosf(hn[0]) * cthv[0];
    float qf1 = __cosf(hn[1]) * cthv[1];
    float qf2 = __cosf(hn[2]) * cthv[2];
    float qf3 = __cosf(hn[3]) * cthv[3];
    int qa = cvt_pk_bf16(qf0, qf1), qb = cvt_pk_bf16(qf2, qf3);
    int oqa = __shfl_xor(qa, 32), oqb = __shfl_xor(qb, 32);
    int4v bqf = hi ? int4v{ ONE2, 0, 0, 0 }
                   : int4v{ qa, qb, oqa, oqb };
    short8 bqfs = __builtin_bit_cast(short8, bqf);

    // ---- FFN: this wave's 8 chunks (F-split), dual accumulators ----
    f32x16 accA = z16, accB = z16;
    const int c0 = fh2 * 8;
    #pragma unroll
    for (int k = 0; k < 8; ++k) {
        const int c = c0 + k;
        short8 aW = wab[(c << 6) + lane];
        f32x16 m1 = __builtin_amdgcn_mfma_f32_32x32x16_bf16(
            aW, bqfs, z16, 0, 0, 0);
        float r0  = fmaxf(m1[0], 0.f),  r1  = fmaxf(m1[1], 0.f);
        float r2  = fmaxf(m1[2], 0.f),  r3  = fmaxf(m1[3], 0.f);
        float r4  = fmaxf(m1[4], 0.f),  r5  = fmaxf(m1[5], 0.f);
        float r6  = fmaxf(m1[6], 0.f),  r7  = fmaxf(m1[7], 0.f);
        float r8  = fmaxf(m1[8], 0.f),  r9  = fmaxf(m1[9], 0.f);
        float r10 = fmaxf(m1[10], 0.f), r11 = fmaxf(m1[11], 0.f);
        float r12 = fmaxf(m1[12], 0.f), r13 = fmaxf(m1[13], 0.f);
        float r14 = fmaxf(m1[14], 0.f), r15 = fmaxf(m1[15], 0.f);
        int4v pA = { cvt_pk_bf16(r0,  r1),  cvt_pk_bf16(r2,  r3),
                     cvt_pk_bf16(r4,  r5),  cvt_pk_bf16(r6,  r7) };
        int4v pB = { cvt_pk_bf16(r8,  r9),  cvt_pk_bf16(r10, r11),
                     cvt_pk_bf16(r12, r13), cvt_pk_bf16(r14, r15) };
        short8 wa0 = w2p[(c << 5) + (hi << 3) + e8];
        short8 wa1 = w2p[(c << 5) + 16 + (hi << 3) + e8];
        accA = __builtin_amdgcn_mfma_f32_32x32x16_bf16(
            wa0, __builtin_bit_cast(short8, pA), accA, 0, 0, 0);
        accB = __builtin_amdgcn_mfma_f32_32x32x16_bf16(
            wa1, __builtin_bit_cast(short8, pB), accB, 0, 0, 0);
    }

    // ---- merge F-halves via LDS ----
    f32x4 part;
    part[0] = accA[0] + accB[0];
    part[1] = accA[1] + accB[1];
    part[2] = accA[2] + accB[2];
    part[3] = accA[3] + accB[3];
    if (fh2 == 1) red[g][lane] = part;
    __syncthreads();

    // ---- epilogue (fhalf=0 waves): +other half, +b2, LN2, store ----
    if (fh2 == 0) {
        f32x4 oth = red[g][lane];
        float oi[4];
        #pragma unroll
        for (int i = 0; i < 4; ++i)
            oi[i] = hn[i] + part[i] + oth[i] + b2[4 * hi + i];
        float ps2 = oi[0] + oi[1] + oi[2] + oi[3];
        float pq2 = oi[0]*oi[0] + oi[1]*oi[1] + oi[2]*oi[2] + oi[3]*oi[3];
        float m2 = (ps2 + __shfl_xor(ps2, 32)) * 0.125f;
        float v2 = (pq2 + __shfl_xor(pq2, 32)) * 0.125f - m2 * m2;
        float rs2 = rsqrtf(v2 + 1e-5f);
        if (valid) {
            f32x4 st;
            #pragma unroll
            for (int i = 0; i < 4; ++i)
                st[i] = (oi[i] - m2) * rs2 * g2[4 * hi + i] + bb2[4 * hi + i];
            *reinterpret_cast<f32x4*>(out + (size_t)T * E + hi * 4) = st;
        }
    }
}

extern "C" void kernel_launch(void* const* d_in, const int* in_sizes, int n_in,
                              void* d_out, int out_size, void* d_ws, size_t ws_size,
                              hipStream_t stream) {
    const float* x       = (const float*)d_in[0];
    const float* Win     = (const float*)d_in[1];
    const float* th_attn = (const float*)d_in[2];
    const float* Wout    = (const float*)d_in[3];
    const float* th_ffn  = (const float*)d_in[4];
    const float* W1      = (const float*)d_in[5];
    const float* b1      = (const float*)d_in[6];
    const float* W2      = (const float*)d_in[7];
    const float* b2      = (const float*)d_in[8];
    const float* g1      = (const float*)d_in[9];
    const float* bb1     = (const float*)d_in[10];
    const float* g2      = (const float*)d_in[11];
    const float* bb2     = (const float*)d_in[12];
    float* out = (float*)d_out;
    (void)d_ws; (void)ws_size;

    const int ntok = in_sizes[0] / E;            // 131072
    const int blocks = (ntok + TPB - 1) / TPB;   // 1024
    qtb_kernel<<<blocks, 512, 0, stream>>>(x, Win, th_attn, Wout, th_ffn,
                                           W1, b1, W2, b2, g1, bb1, g2, bb2,
                                           out, ntok);
}

// Round 13
// 15.083 us; speedup vs baseline: 1.1552x; 1.1552x over previous
//
#include <hip/hip_runtime.h>

// TransformerBlockQuantum: B=32, S=4096, E=8, F=512, fp32 in/out.
// Full-MFMA single kernel. 1024 threads (16 waves), 512 tokens/block, grid 256
// (1 block/CU, 16 waves/CU). Each wave owns 32 tokens; lanes l / l+32 serve
// token (l&31), hi = l>>5 picks the e-half / K-half. All inter-step transposes
// are absorbed into K-slot permutations of the LDS-staged weights.
// Staging split: tid<512 build W1|b1 recs, tid>=512 build W2 recs.
// R13: x loaded BEFORE staging (hides L3-cold HBM miss under staging+barrier);
//      s_setprio(1) around the FFN MFMA cluster (barrier-free diverse waves).
//
//  attn:  D1 = Win·x^T (+theta via K-slots 8/9 vs const 1.0)  [1 mfma]
//         q = cos(D1 regs0-3);  D2 = Wout·q + C(=x residual)  [1 mfma]
//  LN1:   half-split: lane reduces its native 4 elems, cross-half via
//         2x shfl_xor partial sums; E[x^2]-m^2 variance.
//  qf:    4 cos/lane * cth table -> 2 packed words -> 2 shfl -> B-frag.
//  FFN/chunk c:  mid = wab·qf (b1 via K8/9)  [1 mfma, 1 ds];
//         relu = fmaxf + cvt_pk (v_pk_max_i16 = round-8 bug, banned;
//         global-wab-via-prep-kernel = round-10 bug, banned);
//         dual accumulators accA/accB halve the MFMA dep chain  [2 mfma, 2 ds].
//  epilogue: +b2, half-split LN2, coalesced f32x4 store.

typedef __attribute__((ext_vector_type(8)))  short short8;
typedef __attribute__((ext_vector_type(4)))  float f32x4;
typedef __attribute__((ext_vector_type(16))) float f32x16;
typedef __attribute__((ext_vector_type(4)))  int   int4v;

constexpr int E   = 8;
constexpr int F   = 512;
constexpr int TPB = 512;            // tokens per block

static __device__ __forceinline__ int cvt_pk_bf16(float lo, float hi) {
    int r;
    asm("v_cvt_pk_bf16_f32 %0, %1, %2" : "=v"(r) : "v"(lo), "v"(hi));
    return r;
}

// pack {bf16_hi(v), bf16(v - hi)} into one word (K-slot pair vs 1.0,1.0)
static __device__ __forceinline__ int hilo_bf16(float v) {
    unsigned u = __builtin_bit_cast(unsigned, v);
    float fh = __builtin_bit_cast(float, u & 0xFFFF0000u);
    return cvt_pk_bf16(fh, v - fh);
}

__global__ __launch_bounds__(1024, 4) void qtb_kernel(
    const float* __restrict__ x,
    const float* __restrict__ Win,
    const float* __restrict__ th_attn,
    const float* __restrict__ Wout,
    const float* __restrict__ th_ffn,
    const float* __restrict__ W1,
    const float* __restrict__ b1,
    const float* __restrict__ W2,
    const float* __restrict__ b2,
    const float* __restrict__ g1, const float* __restrict__ bb1,
    const float* __restrict__ g2, const float* __restrict__ bb2,
    float* __restrict__ out, int ntok)
{
    __shared__ short8 wab[1024];    // [c][0-31: W1 row 32c+r | 32-63: b1 rec]
    __shared__ short8 w2p[512];     // [c][m][hi][e8] K-permuted W2 recs
    __shared__ short8 attnA[64];    // Win rows / theta recs
    __shared__ short8 woutp[64];    // Wout K-permuted recs
    __shared__ __align__(16) float cth_lds[8];   // cos(th_ffn)

    const int tid  = threadIdx.x;
    const int lane = tid & 63;
    const int wv   = tid >> 6;        // 0..15
    const int t32  = lane & 31;
    const int hi   = lane >> 5;
    const int e8   = t32 & 7;

    // ---- issue x load FIRST: cold-HBM miss hides under staging + barrier --
    const int T = blockIdx.x * TPB + wv * 32 + t32;
    const bool valid = (T < ntok);
    f32x4 x0 = {0.f,0.f,0.f,0.f}, x1 = {0.f,0.f,0.f,0.f};
    if (valid) {
        const f32x4* xv = reinterpret_cast<const f32x4*>(x + (size_t)T * E);
        x0 = xv[0]; x1 = xv[1];
    }

    // ---------------- stage weights (split across thread halves) ----------
    if (tid < 512) {
        // W1 row `tid` -> wab[64*(tid>>5) + (tid&31)]
        const f32x4* w1v = reinterpret_cast<const f32x4*>(W1 + tid * 8);
        f32x4 a = w1v[0], b = w1v[1];
        int4v rw1 = { cvt_pk_bf16(a[0], a[1]), cvt_pk_bf16(a[2], a[3]),
                      cvt_pk_bf16(b[0], b[1]), cvt_pk_bf16(b[2], b[3]) };
        wab[((tid >> 5) << 6) + (tid & 31)] = __builtin_bit_cast(short8, rw1);
        // b1 row `tid` -> wab[.. + 32 + ..]  (hi/lo split, K-slots 8/9)
        int4v rb1 = { hilo_bf16(b1[tid]), 0, 0, 0 };
        wab[((tid >> 5) << 6) + 32 + (tid & 31)] = __builtin_bit_cast(short8, rb1);

        if (tid < 8) cth_lds[tid] = __cosf(th_ffn[tid]);

        if (tid < 64) {           // attnA: lanes 0-31 Win rows, 32-63 theta recs
            const int tt = tid & 31;
            int4v ra = { 0, 0, 0, 0 };
            if (tt < 8) {
                if (tid < 32) {
                    const f32x4* wiv = reinterpret_cast<const f32x4*>(Win + tt * 8);
                    f32x4 wa = wiv[0], wb = wiv[1];
                    ra = int4v{ cvt_pk_bf16(wa[0], wa[1]), cvt_pk_bf16(wa[2], wa[3]),
                                cvt_pk_bf16(wb[0], wb[1]), cvt_pk_bf16(wb[2], wb[3]) };
                } else {
                    ra = int4v{ hilo_bf16(th_attn[tt]), 0, 0, 0 };
                }
            }
            attnA[tid] = __builtin_bit_cast(short8, ra);
        } else if (tid < 128) {   // woutp: rec (t32, hh) = {Wout[t32][4hh..+3]}
            const int l = tid - 64, tt = l & 31, hh = l >> 5;
            int4v ro = { 0, 0, 0, 0 };
            if (tt < 8) {
                const float* wo = Wout + tt * 8 + hh * 4;
                ro.x = cvt_pk_bf16(wo[0], wo[1]);
                ro.y = cvt_pk_bf16(wo[2], wo[3]);
            }
            woutp[l] = __builtin_bit_cast(short8, ro);
        }
    } else {
        // W2 K-permuted rec r = tid-512
        const int r  = tid - 512;
        const int se = r & 7, sh = (r >> 3) & 1, sm = (r >> 4) & 1, sc = r >> 5;
        const int f0 = sc * 32 + sm * 16 + sh * 4;
        const float* wp = W2 + se * F + f0;
        f32x4 p = *reinterpret_cast<const f32x4*>(wp);
        f32x4 q = *reinterpret_cast<const f32x4*>(wp + 8);
        int4v rw2 = { cvt_pk_bf16(p[0], p[1]), cvt_pk_bf16(p[2], p[3]),
                      cvt_pk_bf16(q[0], q[1]), cvt_pk_bf16(q[2], q[3]) };
        w2p[r] = __builtin_bit_cast(short8, rw2);
    }
    __syncthreads();

    // ---------------- per-wave, fully independent --------------------------
    const int ONE2 = 0x3F803F80;            // two bf16 1.0
    const f32x16 z16 = {};

    // ---- attention GEMM1: D1 = Win·x^T + theta ----
    int4v bx = hi ? int4v{ ONE2, 0, 0, 0 }
                  : int4v{ cvt_pk_bf16(x0[0], x0[1]), cvt_pk_bf16(x0[2], x0[3]),
                           cvt_pk_bf16(x1[0], x1[1]), cvt_pk_bf16(x1[2], x1[3]) };
    short8 aA = attnA[lane];
    f32x16 d1 = __builtin_amdgcn_mfma_f32_32x32x16_bf16(
        aA, __builtin_bit_cast(short8, bx), z16, 0, 0, 0);

    // q for f = 4*hi + 0..3 (native per half)
    float qv0 = __cosf(d1[0]), qv1 = __cosf(d1[1]);
    float qv2 = __cosf(d1[2]), qv3 = __cosf(d1[3]);

    // ---- attention GEMM2: D2 = Wout·q + x (residual via C) ----
    int q01 = cvt_pk_bf16(qv0, qv1), q23 = cvt_pk_bf16(qv2, qv3);
    int4v bq2 = { q01, q23, q01, q23 };     // elems 4-7 junk, A has zeros there
    short8 aO = woutp[lane];
    f32x16 c2 = z16;
    c2[0] = hi ? x1[0] : x0[0];
    c2[1] = hi ? x1[1] : x0[1];
    c2[2] = hi ? x1[2] : x0[2];
    c2[3] = hi ? x1[3] : x0[3];
    f32x16 d2 = __builtin_amdgcn_mfma_f32_32x32x16_bf16(
        aO, __builtin_bit_cast(short8, bq2), c2, 0, 0, 0);

    // ---- half-split LN1: lane reduces its native 4 elems (e = 4hi+i) ----
    float s0 = d2[0], s1 = d2[1], s2 = d2[2], s3 = d2[3];
    float ps = s0 + s1 + s2 + s3;
    float pq = s0*s0 + s1*s1 + s2*s2 + s3*s3;
    float mn = (ps + __shfl_xor(ps, 32)) * 0.125f;
    float vr = (pq + __shfl_xor(pq, 32)) * 0.125f - mn * mn;
    float rs = rsqrtf(vr + 1e-5f);
    float hn[4];
    hn[0] = (s0 - mn) * rs * g1[4 * hi + 0] + bb1[4 * hi + 0];
    hn[1] = (s1 - mn) * rs * g1[4 * hi + 1] + bb1[4 * hi + 1];
    hn[2] = (s2 - mn) * rs * g1[4 * hi + 2] + bb1[4 * hi + 2];
    hn[3] = (s3 - mn) * rs * g1[4 * hi + 3] + bb1[4 * hi + 3];

    // ---- qf (4 cos/lane, cth table) + B-frag via 2 shfl ----
    f32x4 cthv = *reinterpret_cast<const f32x4*>(&cth_lds[hi * 4]);
    float qf0 = __cosf(hn[0]) * cthv[0];
    float qf1 = __cosf(hn[1]) * cthv[1];
    float qf2 = __cosf(hn[2]) * cthv[2];
    float qf3 = __cosf(hn[3]) * cthv[3];
    int qa = cvt_pk_bf16(qf0, qf1), qb = cvt_pk_bf16(qf2, qf3);
    int oqa = __shfl_xor(qa, 32), oqb = __shfl_xor(qb, 32);
    int4v bqf = hi ? int4v{ ONE2, 0, 0, 0 }
                   : int4v{ qa, qb, oqa, oqb };
    short8 bqfs = __builtin_bit_cast(short8, bqf);

    // ---- FFN main loop: dual accumulators, setprio around MFMA cluster ----
    f32x16 accA = z16, accB = z16;
    __builtin_amdgcn_s_setprio(1);
    #pragma unroll 4
    for (int c = 0; c < 16; ++c) {
        short8 aW = wab[(c << 6) + lane];
        f32x16 m1 = __builtin_amdgcn_mfma_f32_32x32x16_bf16(
            aW, bqfs, z16, 0, 0, 0);
        float r0  = fmaxf(m1[0], 0.f),  r1  = fmaxf(m1[1], 0.f);
        float r2  = fmaxf(m1[2], 0.f),  r3  = fmaxf(m1[3], 0.f);
        float r4  = fmaxf(m1[4], 0.f),  r5  = fmaxf(m1[5], 0.f);
        float r6  = fmaxf(m1[6], 0.f),  r7  = fmaxf(m1[7], 0.f);
        float r8  = fmaxf(m1[8], 0.f),  r9  = fmaxf(m1[9], 0.f);
        float r10 = fmaxf(m1[10], 0.f), r11 = fmaxf(m1[11], 0.f);
        float r12 = fmaxf(m1[12], 0.f), r13 = fmaxf(m1[13], 0.f);
        float r14 = fmaxf(m1[14], 0.f), r15 = fmaxf(m1[15], 0.f);
        int4v pA = { cvt_pk_bf16(r0,  r1),  cvt_pk_bf16(r2,  r3),
                     cvt_pk_bf16(r4,  r5),  cvt_pk_bf16(r6,  r7) };
        int4v pB = { cvt_pk_bf16(r8,  r9),  cvt_pk_bf16(r10, r11),
                     cvt_pk_bf16(r12, r13), cvt_pk_bf16(r14, r15) };
        short8 wa0 = w2p[(c << 5) + (hi << 3) + e8];
        short8 wa1 = w2p[(c << 5) + 16 + (hi << 3) + e8];
        accA = __builtin_amdgcn_mfma_f32_32x32x16_bf16(
            wa0, __builtin_bit_cast(short8, pA), accA, 0, 0, 0);
        accB = __builtin_amdgcn_mfma_f32_32x32x16_bf16(
            wa1, __builtin_bit_cast(short8, pB), accB, 0, 0, 0);
    }
    __builtin_amdgcn_s_setprio(0);

    // ---- epilogue: +b2, half-split LN2, store ----
    float oi[4];
    #pragma unroll
    for (int i = 0; i < 4; ++i)
        oi[i] = hn[i] + accA[i] + accB[i] + b2[4 * hi + i];
    float ps2 = oi[0] + oi[1] + oi[2] + oi[3];
    float pq2 = oi[0]*oi[0] + oi[1]*oi[1] + oi[2]*oi[2] + oi[3]*oi[3];
    float m2 = (ps2 + __shfl_xor(ps2, 32)) * 0.125f;
    float v2 = (pq2 + __shfl_xor(pq2, 32)) * 0.125f - m2 * m2;
    float rs2 = rsqrtf(v2 + 1e-5f);

    if (valid) {
        f32x4 st;
        #pragma unroll
        for (int i = 0; i < 4; ++i)
            st[i] = (oi[i] - m2) * rs2 * g2[4 * hi + i] + bb2[4 * hi + i];
        *reinterpret_cast<f32x4*>(out + (size_t)T * E + hi * 4) = st;
    }
}

extern "C" void kernel_launch(void* const* d_in, const int* in_sizes, int n_in,
                              void* d_out, int out_size, void* d_ws, size_t ws_size,
                              hipStream_t stream) {
    const float* x       = (const float*)d_in[0];
    const float* Win     = (const float*)d_in[1];
    const float* th_attn = (const float*)d_in[2];
    const float* Wout    = (const float*)d_in[3];
    const float* th_ffn  = (const float*)d_in[4];
    const float* W1      = (const float*)d_in[5];
    const float* b1      = (const float*)d_in[6];
    const float* W2      = (const float*)d_in[7];
    const float* b2      = (const float*)d_in[8];
    const float* g1      = (const float*)d_in[9];
    const float* bb1     = (const float*)d_in[10];
    const float* g2      = (const float*)d_in[11];
    const float* bb2     = (const float*)d_in[12];
    float* out = (float*)d_out;
    (void)d_ws; (void)ws_size;

    const int ntok = in_sizes[0] / E;            // 131072
    const int blocks = (ntok + TPB - 1) / TPB;   // 256
    qtb_kernel<<<blocks, 1024, 0, stream>>>(x, Win, th_attn, Wout, th_ffn,
                                            W1, b1, W2, b2, g1, bb1, g2, bb2,
                                            out, ntok);
}